// Round 2
// baseline (1858.856 us; speedup 1.0000x reference)
//
#include <hip/hip_runtime.h>
#include <hip/hip_bf16.h>

#define B_ 4
#define T_ 2048
#define C_ 2048
#define D_ 2048
#define F_ 8192
#define BT_ (B_*T_)

using bf16 = __hip_bfloat16;
typedef __attribute__((ext_vector_type(8))) short bf16x8;
typedef __attribute__((ext_vector_type(4))) float f32x4;

struct bf4 { bf16 a, b, c, d; };

__device__ __forceinline__ bf4 to_bf4(float x, float y, float z, float w) {
  bf4 r;
  r.a = __float2bfloat16(x); r.b = __float2bfloat16(y);
  r.c = __float2bfloat16(z); r.d = __float2bfloat16(w);
  return r;
}

// ---------------- fp32 -> bf16 conversion (contiguous) ----------------
__global__ __launch_bounds__(256) void cvt_kernel(const float* __restrict__ in,
                                                  bf16* __restrict__ out, int n4) {
  int i = blockIdx.x * blockDim.x + threadIdx.x;
  int stride = gridDim.x * blockDim.x;
  for (; i < n4; i += stride) {
    float4 v = ((const float4*)in)[i];
    ((bf4*)out)[i] = to_bf4(v.x, v.y, v.z, v.w);
  }
}

// ---------------- fp32 -> bf16 conversion of a column slice ----------------
// out[r][j] = in[r][col0 + j], j in [0, cols_out), row stride ld_in
__global__ __launch_bounds__(256) void packcvt_kernel(const float* __restrict__ in,
    bf16* __restrict__ out, int rows, int cols_out, int ld_in, int col0) {
  int n4 = rows * (cols_out >> 2);
  int c4 = cols_out >> 2;
  int i = blockIdx.x * blockDim.x + threadIdx.x;
  int stride = gridDim.x * blockDim.x;
  for (; i < n4; i += stride) {
    int r = i / c4;
    int j4 = i - r * c4;
    float4 v = *(const float4*)(in + (size_t)r * ld_in + col0 + j4 * 4);
    ((bf4*)out)[i] = to_bf4(v.x, v.y, v.z, v.w);
  }
}

// ---------------- block-wide reduce of 4 values (256 threads) ----------------
__device__ __forceinline__ void block_reduce4(float v[4], float out[4]) {
  #pragma unroll
  for (int i = 0; i < 4; ++i)
    #pragma unroll
    for (int off = 1; off < 64; off <<= 1)
      v[i] += __shfl_xor(v[i], off);
  __shared__ float red[4][4];
  int wave = threadIdx.x >> 6, lane = threadIdx.x & 63;
  if (lane == 0) {
    red[wave][0] = v[0]; red[wave][1] = v[1];
    red[wave][2] = v[2]; red[wave][3] = v[3];
  }
  __syncthreads();
  #pragma unroll
  for (int i = 0; i < 4; ++i)
    out[i] = red[0][i] + red[1][i] + red[2][i] + red[3][i];
}

// ---------------- fused LN + token-shift mix (TimeMix: 3 outputs) ----------------
__global__ __launch_bounds__(256) void mix1f_kernel(const float* __restrict__ x,
    const float* __restrict__ w, const float* __restrict__ b,
    const float* __restrict__ tmk, const float* __restrict__ tmv, const float* __restrict__ tmr,
    bf16* __restrict__ xk, bf16* __restrict__ xv, bf16* __restrict__ xr) {
  const int row = blockIdx.x;
  const int t = row & (T_ - 1);
  const bool hasPrev = (t != 0);
  const int tid = threadIdx.x;
  const float* xc = x + (size_t)row * C_;
  const float* xp = xc - C_;
  float c[8], p[8];
  *(float4*)&c[0] = *(const float4*)(xc + tid * 4);
  *(float4*)&c[4] = *(const float4*)(xc + tid * 4 + 1024);
  if (hasPrev) {
    *(float4*)&p[0] = *(const float4*)(xp + tid * 4);
    *(float4*)&p[4] = *(const float4*)(xp + tid * 4 + 1024);
  } else {
    #pragma unroll
    for (int j = 0; j < 8; ++j) p[j] = 0.f;
  }
  float v[4] = {0.f, 0.f, 0.f, 0.f}, tot[4];
  #pragma unroll
  for (int j = 0; j < 8; ++j) {
    v[0] += c[j]; v[1] += c[j] * c[j];
    v[2] += p[j]; v[3] += p[j] * p[j];
  }
  block_reduce4(v, tot);
  const float muc = tot[0] * (1.f / C_);
  const float rsc = rsqrtf(tot[1] * (1.f / C_) - muc * muc + 1e-5f);
  const float mup = tot[2] * (1.f / C_);
  const float rsp = rsqrtf(tot[3] * (1.f / C_) - mup * mup + 1e-5f);
  float wv[8], bv[8], mk[8], mv[8], mr[8];
  #pragma unroll
  for (int half = 0; half < 2; ++half) {
    int i = tid * 4 + half * 1024;
    *(float4*)&wv[half*4] = *(const float4*)(w + i);
    *(float4*)&bv[half*4] = *(const float4*)(b + i);
    *(float4*)&mk[half*4] = *(const float4*)(tmk + i);
    *(float4*)&mv[half*4] = *(const float4*)(tmv + i);
    *(float4*)&mr[half*4] = *(const float4*)(tmr + i);
  }
  float ok[8], ov[8], orr[8];
  #pragma unroll
  for (int j = 0; j < 8; ++j) {
    float h  = (c[j] - muc) * rsc * wv[j] + bv[j];
    float hh = hasPrev ? ((p[j] - mup) * rsp * wv[j] + bv[j]) : 0.f;
    ok[j]  = hh + mk[j] * (h - hh);
    ov[j]  = hh + mv[j] * (h - hh);
    orr[j] = hh + mr[j] * (h - hh);
  }
  size_t ro = (size_t)row * C_;
  #pragma unroll
  for (int half = 0; half < 2; ++half) {
    int i = tid * 4 + half * 1024;
    *(bf4*)(xk + ro + i) = to_bf4(ok[half*4], ok[half*4+1], ok[half*4+2], ok[half*4+3]);
    *(bf4*)(xv + ro + i) = to_bf4(ov[half*4], ov[half*4+1], ov[half*4+2], ov[half*4+3]);
    *(bf4*)(xr + ro + i) = to_bf4(orr[half*4], orr[half*4+1], orr[half*4+2], orr[half*4+3]);
  }
}

// ---------------- fused LN + token-shift mix (ChannelMix: 2 outputs) ----------------
__global__ __launch_bounds__(256) void mix2f_kernel(const float* __restrict__ x,
    const float* __restrict__ w, const float* __restrict__ b,
    const float* __restrict__ cmk, const float* __restrict__ cmr,
    bf16* __restrict__ xk2, bf16* __restrict__ xr2) {
  const int row = blockIdx.x;
  const int t = row & (T_ - 1);
  const bool hasPrev = (t != 0);
  const int tid = threadIdx.x;
  const float* xc = x + (size_t)row * C_;
  const float* xp = xc - C_;
  float c[8], p[8];
  *(float4*)&c[0] = *(const float4*)(xc + tid * 4);
  *(float4*)&c[4] = *(const float4*)(xc + tid * 4 + 1024);
  if (hasPrev) {
    *(float4*)&p[0] = *(const float4*)(xp + tid * 4);
    *(float4*)&p[4] = *(const float4*)(xp + tid * 4 + 1024);
  } else {
    #pragma unroll
    for (int j = 0; j < 8; ++j) p[j] = 0.f;
  }
  float v[4] = {0.f, 0.f, 0.f, 0.f}, tot[4];
  #pragma unroll
  for (int j = 0; j < 8; ++j) {
    v[0] += c[j]; v[1] += c[j] * c[j];
    v[2] += p[j]; v[3] += p[j] * p[j];
  }
  block_reduce4(v, tot);
  const float muc = tot[0] * (1.f / C_);
  const float rsc = rsqrtf(tot[1] * (1.f / C_) - muc * muc + 1e-5f);
  const float mup = tot[2] * (1.f / C_);
  const float rsp = rsqrtf(tot[3] * (1.f / C_) - mup * mup + 1e-5f);
  float wv[8], bv[8], mk[8], mr[8];
  #pragma unroll
  for (int half = 0; half < 2; ++half) {
    int i = tid * 4 + half * 1024;
    *(float4*)&wv[half*4] = *(const float4*)(w + i);
    *(float4*)&bv[half*4] = *(const float4*)(b + i);
    *(float4*)&mk[half*4] = *(const float4*)(cmk + i);
    *(float4*)&mr[half*4] = *(const float4*)(cmr + i);
  }
  float ok[8], orr[8];
  #pragma unroll
  for (int j = 0; j < 8; ++j) {
    float h  = (c[j] - muc) * rsc * wv[j] + bv[j];
    float hh = hasPrev ? ((p[j] - mup) * rsp * wv[j] + bv[j]) : 0.f;
    ok[j]  = hh + mk[j] * (h - hh);
    orr[j] = hh + mr[j] * (h - hh);
  }
  size_t ro = (size_t)row * C_;
  #pragma unroll
  for (int half = 0; half < 2; ++half) {
    int i = tid * 4 + half * 1024;
    *(bf4*)(xk2 + ro + i) = to_bf4(ok[half*4], ok[half*4+1], ok[half*4+2], ok[half*4+3]);
    *(bf4*)(xr2 + ro + i) = to_bf4(orr[half*4], orr[half*4+1], orr[half*4+2], orr[half*4+3]);
  }
}

// ---------------- WKV recurrence: one thread per (b,d) ----------------
__global__ __launch_bounds__(256) void wkv_kernel(
    const bf16* __restrict__ kp, const bf16* __restrict__ vp, const bf16* __restrict__ rp,
    const float* __restrict__ td, const float* __restrict__ tfp,
    bf16* __restrict__ rwkv) {
  const int g = blockIdx.x * 256 + threadIdx.x;   // 0..B*D-1
  const int b = g >> 11;
  const int d = g & (D_ - 1);
  const size_t base = (size_t)b * T_ * D_ + d;
  const float w = -__expf(td[d]);
  const float u = tfp[d];
  float aa = 0.f, bb = 0.f, pp = -1e38f;
  constexpr int U = 8;
  float kb[U], vb[U], rb[U];
  #pragma unroll
  for (int j = 0; j < U; ++j) {
    size_t o = base + (size_t)j * D_;
    kb[j] = __bfloat162float(kp[o]);
    vb[j] = __bfloat162float(vp[o]);
    rb[j] = __bfloat162float(rp[o]);
  }
  for (int t0 = 0; t0 < T_; t0 += U) {
    float kc[U], vc[U], rc[U];
    #pragma unroll
    for (int j = 0; j < U; ++j) { kc[j] = kb[j]; vc[j] = vb[j]; rc[j] = rb[j]; }
    if (t0 + U < T_) {
      #pragma unroll
      for (int j = 0; j < U; ++j) {
        size_t o = base + (size_t)(t0 + U + j) * D_;
        kb[j] = __bfloat162float(kp[o]);
        vb[j] = __bfloat162float(vp[o]);
        rb[j] = __bfloat162float(rp[o]);
      }
    }
    #pragma unroll
    for (int j = 0; j < U; ++j) {
      float kt = kc[j], vt = vc[j];
      float ww = u + kt;
      float p = fmaxf(pp, ww);
      float e1 = __expf(pp - p);
      float e2 = __expf(ww - p);
      float outv = (e1 * aa + e2 * vt) / (e1 * bb + e2);
      float sr = 1.f / (1.f + __expf(-rc[j]));
      rwkv[base + (size_t)(t0 + j) * D_] = __float2bfloat16(sr * outv);
      float ww2 = pp + w;
      float p2 = fmaxf(ww2, kt);
      float e1b = __expf(ww2 - p2);
      float e2b = __expf(kt - p2);
      aa = e1b * aa + e2b * vt;
      bb = e1b * bb + e2b;
      pp = p2;
    }
  }
}

// ---------------- bf16 MFMA GEMM: C[M][N] = A[M][K] * Bt[N][K]^T ----------------
// 128x128 tile, 4 waves (2x2), BK=64, global_load_lds staging, 16x16x32 MFMA.
// EPI: 0 = bf16 store, 1 = relu^2 bf16, 2 = fp32 add-residual, 3 = sigmoid bf16,
//      4 = fp32 add-residual + sig-gate (addP may alias outF; each elem written once)
template<int EPI>
__global__ __launch_bounds__(256) void gemm_bt(
    const bf16* __restrict__ A, const bf16* __restrict__ Bt,
    int M, int N, int K,
    float* __restrict__ outF, bf16* __restrict__ outB,
    const float* __restrict__ addP, const bf16* __restrict__ sigP) {
  __shared__ bf16 As[128 * 64];
  __shared__ bf16 Bs[128 * 64];
  const int tid = threadIdx.x;
  const int wave = tid >> 6, lane = tid & 63;
  const int tileM = blockIdx.y * 128, tileN = blockIdx.x * 128;
  const int wm = (wave >> 1) * 64, wn = (wave & 1) * 64;

  f32x4 acc[4][4] = {};

  const int srow = lane >> 3;        // 0..7
  const int scol = (lane & 7) * 8;   // element offset in K

  for (int k0 = 0; k0 < K; k0 += 64) {
    __syncthreads();
    #pragma unroll
    for (int i = 0; i < 4; ++i) {
      const int rA = i * 32 + wave * 8;
      const bf16* gA = A + (size_t)(tileM + rA + srow) * K + k0 + scol;
      __builtin_amdgcn_global_load_lds(
          (const __attribute__((address_space(1))) void*)gA,
          (__attribute__((address_space(3))) void*)(As + rA * 64), 16, 0, 0);
      const bf16* gB = Bt + (size_t)(tileN + rA + srow) * K + k0 + scol;
      __builtin_amdgcn_global_load_lds(
          (const __attribute__((address_space(1))) void*)gB,
          (__attribute__((address_space(3))) void*)(Bs + rA * 64), 16, 0, 0);
    }
    __syncthreads();
    #pragma unroll
    for (int kk = 0; kk < 2; ++kk) {
      bf16x8 af[4], bfv[4];
      #pragma unroll
      for (int im = 0; im < 4; ++im)
        af[im] = *(const bf16x8*)(As + (wm + im * 16 + (lane & 15)) * 64 + kk * 32 + (lane >> 4) * 8);
      #pragma unroll
      for (int in = 0; in < 4; ++in)
        bfv[in] = *(const bf16x8*)(Bs + (wn + in * 16 + (lane & 15)) * 64 + kk * 32 + (lane >> 4) * 8);
      #pragma unroll
      for (int im = 0; im < 4; ++im)
        #pragma unroll
        for (int in = 0; in < 4; ++in)
          acc[im][in] = __builtin_amdgcn_mfma_f32_16x16x32_bf16(af[im], bfv[in], acc[im][in], 0, 0, 0);
    }
  }

  const int erow0 = tileM + wm + (lane >> 4) * 4;
  const int ecol0 = tileN + wn + (lane & 15);
  #pragma unroll
  for (int im = 0; im < 4; ++im) {
    #pragma unroll
    for (int in = 0; in < 4; ++in) {
      #pragma unroll
      for (int r = 0; r < 4; ++r) {
        const int grow = erow0 + im * 16 + r;
        const int gcol = ecol0 + in * 16;
        const size_t idx = (size_t)grow * N + gcol;
        const float val = acc[im][in][r];
        if constexpr (EPI == 0) {
          outB[idx] = __float2bfloat16(val);
        } else if constexpr (EPI == 1) {
          float tt = fmaxf(val, 0.f);
          outB[idx] = __float2bfloat16(tt * tt);
        } else if constexpr (EPI == 2) {
          outF[idx] = addP[idx] + val;
        } else if constexpr (EPI == 3) {
          outB[idx] = __float2bfloat16(1.f / (1.f + __expf(-val)));
        } else {
          outF[idx] = addP[idx] + __bfloat162float(sigP[idx]) * val;
        }
      }
    }
  }
}

// ---------------- launch ----------------
extern "C" void kernel_launch(void* const* d_in, const int* in_sizes, int n_in,
                              void* d_out, int out_size, void* d_ws, size_t ws_size,
                              hipStream_t stream) {
  const float* x    = (const float*)d_in[0];
  const float* ln1w = (const float*)d_in[1];
  const float* ln1b = (const float*)d_in[2];
  const float* ln2w = (const float*)d_in[3];
  const float* ln2b = (const float*)d_in[4];
  const float* tmk  = (const float*)d_in[5];
  const float* tmv  = (const float*)d_in[6];
  const float* tmr  = (const float*)d_in[7];
  const float* td   = (const float*)d_in[8];
  const float* tf   = (const float*)d_in[9];
  const float* Wk   = (const float*)d_in[10];
  const float* Wv   = (const float*)d_in[11];
  const float* Wr   = (const float*)d_in[12];
  const float* Wo   = (const float*)d_in[13];
  const float* cmk  = (const float*)d_in[14];
  const float* cmr  = (const float*)d_in[15];
  const float* Wck  = (const float*)d_in[16];
  const float* Wcv  = (const float*)d_in[17];
  const float* Wcr  = (const float*)d_in[18];
  float* out = (float*)d_out;

  char* ws = (char*)d_ws;
  const size_t MB = 1ull << 20;
  // Slots (32 MiB each): R0 = weights (rotating), R1..R3 activations, R4(+R5) = k / kf
  bf16* R0 = (bf16*)(ws + 0 * MB);
  bf16* R1 = (bf16*)(ws + 32 * MB);
  bf16* R2 = (bf16*)(ws + 64 * MB);
  bf16* R3 = (bf16*)(ws + 96 * MB);
  bf16* R4 = (bf16*)(ws + 128 * MB);

  // F-dim split for ChannelMix so kf fits: S=1 needs 256 MiB ws, S=2 -> 192, S=4 -> 160
  int S = (ws_size >= 256 * MB) ? 1 : (ws_size >= 192 * MB ? 2 : 4);
  const int FS = F_ / S;

  bf16* xk = R1, *xv = R2, *xr = R3;
  bf16* k_ = R4, *v_ = R1, *r_ = R2, *rwkv = R3;
  bf16* xk2 = R1, *xr2 = R2, *sig = R3, *kf = R4;

  // --- TimeMix ---
  mix1f_kernel<<<BT_, 256, 0, stream>>>(x, ln1w, ln1b, tmk, tmv, tmr, xk, xv, xr);
  cvt_kernel<<<1024, 256, 0, stream>>>(Wk, R0, D_ * C_ / 4);
  gemm_bt<0><<<dim3(D_/128, BT_/128), 256, 0, stream>>>(xk, R0, BT_, D_, C_, nullptr, k_, nullptr, nullptr);
  cvt_kernel<<<1024, 256, 0, stream>>>(Wv, R0, D_ * C_ / 4);
  gemm_bt<0><<<dim3(D_/128, BT_/128), 256, 0, stream>>>(xv, R0, BT_, D_, C_, nullptr, v_, nullptr, nullptr);
  cvt_kernel<<<1024, 256, 0, stream>>>(Wr, R0, D_ * C_ / 4);
  gemm_bt<0><<<dim3(D_/128, BT_/128), 256, 0, stream>>>(xr, R0, BT_, D_, C_, nullptr, r_, nullptr, nullptr);
  wkv_kernel<<<B_ * D_ / 256, 256, 0, stream>>>(k_, v_, r_, td, tf, rwkv);
  cvt_kernel<<<1024, 256, 0, stream>>>(Wo, R0, C_ * D_ / 4);
  gemm_bt<2><<<dim3(C_/128, BT_/128), 256, 0, stream>>>(rwkv, R0, BT_, C_, D_, out, nullptr, x, nullptr);

  // --- ChannelMix ---
  mix2f_kernel<<<BT_, 256, 0, stream>>>(out, ln2w, ln2b, cmk, cmr, xk2, xr2);
  cvt_kernel<<<1024, 256, 0, stream>>>(Wcr, R0, C_ * C_ / 4);
  gemm_bt<3><<<dim3(C_/128, BT_/128), 256, 0, stream>>>(xr2, R0, BT_, C_, C_, nullptr, sig, nullptr, nullptr);
  for (int h = 0; h < S; ++h) {
    // Wck slice: contiguous rows [h*FS, (h+1)*FS)
    cvt_kernel<<<1024, 256, 0, stream>>>(Wck + (size_t)h * FS * C_, R0, FS * C_ / 4);
    gemm_bt<1><<<dim3(FS/128, BT_/128), 256, 0, stream>>>(xk2, R0, BT_, FS, C_, nullptr, kf, nullptr, nullptr);
    // Wcv slice: columns [h*FS, (h+1)*FS) of [C_][F_] -> packed [C_][FS]
    packcvt_kernel<<<1024, 256, 0, stream>>>(Wcv, R0, C_, FS, F_, h * FS);
    gemm_bt<4><<<dim3(C_/128, BT_/128), 256, 0, stream>>>(kf, R0, BT_, C_, FS, out, nullptr, out, sig);
  }
}

// Round 3
// 1335.383 us; speedup vs baseline: 1.3920x; 1.3920x over previous
//
#include <hip/hip_runtime.h>
#include <hip/hip_bf16.h>

#define B_ 4
#define T_ 2048
#define C_ 2048
#define D_ 2048
#define F_ 8192
#define BT_ (B_*T_)

using bf16 = __hip_bfloat16;
typedef __attribute__((ext_vector_type(8))) short bf16x8;
typedef __attribute__((ext_vector_type(4))) float f32x4;

struct bf4 { bf16 a, b, c, d; };

__device__ __forceinline__ bf4 to_bf4(float x, float y, float z, float w) {
  bf4 r;
  r.a = __float2bfloat16(x); r.b = __float2bfloat16(y);
  r.c = __float2bfloat16(z); r.d = __float2bfloat16(w);
  return r;
}

// ---------------- fp32 -> bf16 conversion (contiguous) ----------------
__global__ __launch_bounds__(256) void cvt_kernel(const float* __restrict__ in,
                                                  bf16* __restrict__ out, int n4) {
  int i = blockIdx.x * blockDim.x + threadIdx.x;
  int stride = gridDim.x * blockDim.x;
  for (; i < n4; i += stride) {
    float4 v = ((const float4*)in)[i];
    ((bf4*)out)[i] = to_bf4(v.x, v.y, v.z, v.w);
  }
}

// ---------------- fp32 -> bf16 conversion of a column slice ----------------
__global__ __launch_bounds__(256) void packcvt_kernel(const float* __restrict__ in,
    bf16* __restrict__ out, int rows, int cols_out, int ld_in, int col0) {
  int n4 = rows * (cols_out >> 2);
  int c4 = cols_out >> 2;
  int i = blockIdx.x * blockDim.x + threadIdx.x;
  int stride = gridDim.x * blockDim.x;
  for (; i < n4; i += stride) {
    int r = i / c4;
    int j4 = i - r * c4;
    float4 v = *(const float4*)(in + (size_t)r * ld_in + col0 + j4 * 4);
    ((bf4*)out)[i] = to_bf4(v.x, v.y, v.z, v.w);
  }
}

// ---------------- block-wide reduce of 4 values (256 threads) ----------------
__device__ __forceinline__ void block_reduce4(float v[4], float out[4]) {
  #pragma unroll
  for (int i = 0; i < 4; ++i)
    #pragma unroll
    for (int off = 1; off < 64; off <<= 1)
      v[i] += __shfl_xor(v[i], off);
  __shared__ float red[4][4];
  int wave = threadIdx.x >> 6, lane = threadIdx.x & 63;
  if (lane == 0) {
    red[wave][0] = v[0]; red[wave][1] = v[1];
    red[wave][2] = v[2]; red[wave][3] = v[3];
  }
  __syncthreads();
  #pragma unroll
  for (int i = 0; i < 4; ++i)
    out[i] = red[0][i] + red[1][i] + red[2][i] + red[3][i];
}

// ---------------- fused LN + token-shift mix (TimeMix: 3 outputs) ----------------
__global__ __launch_bounds__(256) void mix1f_kernel(const float* __restrict__ x,
    const float* __restrict__ w, const float* __restrict__ b,
    const float* __restrict__ tmk, const float* __restrict__ tmv, const float* __restrict__ tmr,
    bf16* __restrict__ xk, bf16* __restrict__ xv, bf16* __restrict__ xr) {
  const int row = blockIdx.x;
  const int t = row & (T_ - 1);
  const bool hasPrev = (t != 0);
  const int tid = threadIdx.x;
  const float* xc = x + (size_t)row * C_;
  const float* xp = xc - C_;
  float c[8], p[8];
  *(float4*)&c[0] = *(const float4*)(xc + tid * 4);
  *(float4*)&c[4] = *(const float4*)(xc + tid * 4 + 1024);
  if (hasPrev) {
    *(float4*)&p[0] = *(const float4*)(xp + tid * 4);
    *(float4*)&p[4] = *(const float4*)(xp + tid * 4 + 1024);
  } else {
    #pragma unroll
    for (int j = 0; j < 8; ++j) p[j] = 0.f;
  }
  float v[4] = {0.f, 0.f, 0.f, 0.f}, tot[4];
  #pragma unroll
  for (int j = 0; j < 8; ++j) {
    v[0] += c[j]; v[1] += c[j] * c[j];
    v[2] += p[j]; v[3] += p[j] * p[j];
  }
  block_reduce4(v, tot);
  const float muc = tot[0] * (1.f / C_);
  const float rsc = rsqrtf(tot[1] * (1.f / C_) - muc * muc + 1e-5f);
  const float mup = tot[2] * (1.f / C_);
  const float rsp = rsqrtf(tot[3] * (1.f / C_) - mup * mup + 1e-5f);
  float wv[8], bv[8], mk[8], mv[8], mr[8];
  #pragma unroll
  for (int half = 0; half < 2; ++half) {
    int i = tid * 4 + half * 1024;
    *(float4*)&wv[half*4] = *(const float4*)(w + i);
    *(float4*)&bv[half*4] = *(const float4*)(b + i);
    *(float4*)&mk[half*4] = *(const float4*)(tmk + i);
    *(float4*)&mv[half*4] = *(const float4*)(tmv + i);
    *(float4*)&mr[half*4] = *(const float4*)(tmr + i);
  }
  float ok[8], ov[8], orr[8];
  #pragma unroll
  for (int j = 0; j < 8; ++j) {
    float h  = (c[j] - muc) * rsc * wv[j] + bv[j];
    float hh = hasPrev ? ((p[j] - mup) * rsp * wv[j] + bv[j]) : 0.f;
    ok[j]  = hh + mk[j] * (h - hh);
    ov[j]  = hh + mv[j] * (h - hh);
    orr[j] = hh + mr[j] * (h - hh);
  }
  size_t ro = (size_t)row * C_;
  #pragma unroll
  for (int half = 0; half < 2; ++half) {
    int i = tid * 4 + half * 1024;
    *(bf4*)(xk + ro + i) = to_bf4(ok[half*4], ok[half*4+1], ok[half*4+2], ok[half*4+3]);
    *(bf4*)(xv + ro + i) = to_bf4(ov[half*4], ov[half*4+1], ov[half*4+2], ov[half*4+3]);
    *(bf4*)(xr + ro + i) = to_bf4(orr[half*4], orr[half*4+1], orr[half*4+2], orr[half*4+3]);
  }
}

// ---------------- fused LN + token-shift mix (ChannelMix: 2 outputs) ----------------
__global__ __launch_bounds__(256) void mix2f_kernel(const float* __restrict__ x,
    const float* __restrict__ w, const float* __restrict__ b,
    const float* __restrict__ cmk, const float* __restrict__ cmr,
    bf16* __restrict__ xk2, bf16* __restrict__ xr2) {
  const int row = blockIdx.x;
  const int t = row & (T_ - 1);
  const bool hasPrev = (t != 0);
  const int tid = threadIdx.x;
  const float* xc = x + (size_t)row * C_;
  const float* xp = xc - C_;
  float c[8], p[8];
  *(float4*)&c[0] = *(const float4*)(xc + tid * 4);
  *(float4*)&c[4] = *(const float4*)(xc + tid * 4 + 1024);
  if (hasPrev) {
    *(float4*)&p[0] = *(const float4*)(xp + tid * 4);
    *(float4*)&p[4] = *(const float4*)(xp + tid * 4 + 1024);
  } else {
    #pragma unroll
    for (int j = 0; j < 8; ++j) p[j] = 0.f;
  }
  float v[4] = {0.f, 0.f, 0.f, 0.f}, tot[4];
  #pragma unroll
  for (int j = 0; j < 8; ++j) {
    v[0] += c[j]; v[1] += c[j] * c[j];
    v[2] += p[j]; v[3] += p[j] * p[j];
  }
  block_reduce4(v, tot);
  const float muc = tot[0] * (1.f / C_);
  const float rsc = rsqrtf(tot[1] * (1.f / C_) - muc * muc + 1e-5f);
  const float mup = tot[2] * (1.f / C_);
  const float rsp = rsqrtf(tot[3] * (1.f / C_) - mup * mup + 1e-5f);
  float wv[8], bv[8], mk[8], mr[8];
  #pragma unroll
  for (int half = 0; half < 2; ++half) {
    int i = tid * 4 + half * 1024;
    *(float4*)&wv[half*4] = *(const float4*)(w + i);
    *(float4*)&bv[half*4] = *(const float4*)(b + i);
    *(float4*)&mk[half*4] = *(const float4*)(cmk + i);
    *(float4*)&mr[half*4] = *(const float4*)(cmr + i);
  }
  float ok[8], orr[8];
  #pragma unroll
  for (int j = 0; j < 8; ++j) {
    float h  = (c[j] - muc) * rsc * wv[j] + bv[j];
    float hh = hasPrev ? ((p[j] - mup) * rsp * wv[j] + bv[j]) : 0.f;
    ok[j]  = hh + mk[j] * (h - hh);
    orr[j] = hh + mr[j] * (h - hh);
  }
  size_t ro = (size_t)row * C_;
  #pragma unroll
  for (int half = 0; half < 2; ++half) {
    int i = tid * 4 + half * 1024;
    *(bf4*)(xk2 + ro + i) = to_bf4(ok[half*4], ok[half*4+1], ok[half*4+2], ok[half*4+3]);
    *(bf4*)(xr2 + ro + i) = to_bf4(orr[half*4], orr[half*4+1], orr[half*4+2], orr[half*4+3]);
  }
}

// ---------------- WKV recurrence: one thread per (b,d) ----------------
__global__ __launch_bounds__(256) void wkv_kernel(
    const bf16* __restrict__ kp, const bf16* __restrict__ vp, const bf16* __restrict__ rp,
    const float* __restrict__ td, const float* __restrict__ tfp,
    bf16* __restrict__ rwkv) {
  const int g = blockIdx.x * 256 + threadIdx.x;   // 0..B*D-1
  const int b = g >> 11;
  const int d = g & (D_ - 1);
  const size_t base = (size_t)b * T_ * D_ + d;
  const float w = -__expf(td[d]);
  const float u = tfp[d];
  float aa = 0.f, bb = 0.f, pp = -1e38f;
  constexpr int U = 8;
  float kb[U], vb[U], rb[U];
  #pragma unroll
  for (int j = 0; j < U; ++j) {
    size_t o = base + (size_t)j * D_;
    kb[j] = __bfloat162float(kp[o]);
    vb[j] = __bfloat162float(vp[o]);
    rb[j] = __bfloat162float(rp[o]);
  }
  for (int t0 = 0; t0 < T_; t0 += U) {
    float kc[U], vc[U], rc[U];
    #pragma unroll
    for (int j = 0; j < U; ++j) { kc[j] = kb[j]; vc[j] = vb[j]; rc[j] = rb[j]; }
    if (t0 + U < T_) {
      #pragma unroll
      for (int j = 0; j < U; ++j) {
        size_t o = base + (size_t)(t0 + U + j) * D_;
        kb[j] = __bfloat162float(kp[o]);
        vb[j] = __bfloat162float(vp[o]);
        rb[j] = __bfloat162float(rp[o]);
      }
    }
    #pragma unroll
    for (int j = 0; j < U; ++j) {
      float kt = kc[j], vt = vc[j];
      float ww = u + kt;
      float p = fmaxf(pp, ww);
      float e1 = __expf(pp - p);
      float e2 = __expf(ww - p);
      float outv = (e1 * aa + e2 * vt) / (e1 * bb + e2);
      float sr = 1.f / (1.f + __expf(-rc[j]));
      rwkv[base + (size_t)(t0 + j) * D_] = __float2bfloat16(sr * outv);
      float ww2 = pp + w;
      float p2 = fmaxf(ww2, kt);
      float e1b = __expf(ww2 - p2);
      float e2b = __expf(kt - p2);
      aa = e1b * aa + e2b * vt;
      bb = e1b * bb + e2b;
      pp = p2;
    }
  }
}

// ================= 256x256 8-phase bf16 MFMA GEMM =================
// C[M][N] = A[M][K] * Bt[N][K]^T.  512 threads = 8 waves (2M x 4N).
// BK=64 per K-tile; 2x double-buffered LDS (128 KiB); per-phase:
// {ds_read frags | stage half-tile via global_load_lds} -> raw barrier ->
// setprio(1) 16x MFMA setprio(0) -> barrier.  Counted vmcnt(4) once per
// K-tile (never 0 in steady state).  XOR swizzle byte^=((row&7)<<4) applied
// on the global SOURCE of the staging and on the ds_read address (rule #21).
// EPI: 0 bf16, 1 relu^2 bf16, 2 fp32 add-res, 3 sigmoid bf16, 4 add-res+sig-gate.
template<int EPI>
__global__ __launch_bounds__(512, 2) void gemm256(
    const bf16* __restrict__ A, const bf16* __restrict__ Bt,
    int N, int K,
    float* __restrict__ outF, bf16* __restrict__ outB,
    const float* __restrict__ addP, const bf16* __restrict__ sigP) {
  __shared__ alignas(16) char lds[131072];   // A: [0,64K) , B: [64K,128K)
  const int tid = threadIdx.x;
  const int wid = tid >> 6, lane = tid & 63;
  const int wm = wid >> 2, wn = wid & 3;

  // T1: bijective XCD swizzle (grid % 8 == 0 by construction)
  const int nwg = gridDim.x;
  const int id = blockIdx.x;
  const int cpx = nwg >> 3;
  const int sid = (id & 7) * cpx + (id >> 3);
  const int nx = N >> 8;
  const int by = sid / nx, bx = sid - by * nx;
  const int tileM = by * 256, tileN = bx * 256;

  const int NT = K >> 6;

  // staging geometry (per half-tile: 128 rows x 64 bf16, row = 128 B)
  const int srow_lo = wid * 8 + (lane >> 3);                 // + j*64
  const int scel = ((lane & 7) ^ (lane >> 3)) << 3;          // swizzled col (elems)

  auto stageA = [&](int tau, int h) {
    if (tau >= NT) return;
    const bf16* gb = A + (size_t)(tileM + h * 128) * K + tau * 64;
    char* lb = lds + (tau & 1) * 32768 + h * 16384 + wid * 1024;
    #pragma unroll
    for (int j = 0; j < 2; ++j) {
      const bf16* g = gb + (size_t)(srow_lo + j * 64) * K + scel;
      __builtin_amdgcn_global_load_lds(
          (const __attribute__((address_space(1))) void*)g,
          (__attribute__((address_space(3))) void*)(lb + j * 8192), 16, 0, 0);
    }
  };
  auto stageB = [&](int tau, int h) {
    if (tau >= NT) return;
    const bf16* gb = Bt + (size_t)(tileN + h * 128) * K + tau * 64;
    char* lb = lds + 65536 + (tau & 1) * 32768 + h * 16384 + wid * 1024;
    #pragma unroll
    for (int j = 0; j < 2; ++j) {
      const bf16* g = gb + (size_t)(srow_lo + j * 64) * K + scel;
      __builtin_amdgcn_global_load_lds(
          (const __attribute__((address_space(1))) void*)g,
          (__attribute__((address_space(3))) void*)(lb + j * 8192), 16, 0, 0);
    }
  };

  // fragment read addressing (bytes), swizzle folded in
  const int lane15 = lane & 15;
  const int kswz0 = ((lane >> 4) * 16) ^ ((lane & 7) << 4);
  const int aBase = (wm * 128 + lane15) * 128;
  const int bBase = (wn * 64 + lane15) * 128;

  f32x4 acc[8][4] = {};

  // prologue: 6 half-tiles in flight, drain to 4 instrs (B(1) stays out)
  stageB(0, 0); stageB(0, 1); stageA(0, 0); stageA(0, 1); stageB(1, 0); stageB(1, 1);
  asm volatile("s_waitcnt vmcnt(4)" : : : "memory");
  __builtin_amdgcn_s_barrier();
  __builtin_amdgcn_sched_barrier(0);

  for (int t = 0; t < NT; ++t) {
    const char* Ab = lds + (t & 1) * 32768;
    const char* Bb = lds + 65536 + (t & 1) * 32768;
    bf16x8 bfr[4][2];
    #pragma unroll
    for (int q = 0; q < 4; ++q) {
      // ---- ds reads for this phase ----
      if (q == 0) {
        #pragma unroll
        for (int n = 0; n < 4; ++n) {
          bfr[n][0] = *(const bf16x8*)(Bb + bBase + n * 2048 + kswz0);
          bfr[n][1] = *(const bf16x8*)(Bb + bBase + n * 2048 + (kswz0 ^ 64));
        }
      }
      bf16x8 am[2][2];
      #pragma unroll
      for (int mm = 0; mm < 2; ++mm) {
        am[mm][0] = *(const bf16x8*)(Ab + aBase + q * 4096 + mm * 2048 + kswz0);
        am[mm][1] = *(const bf16x8*)(Ab + aBase + q * 4096 + mm * 2048 + (kswz0 ^ 64));
      }
      __builtin_amdgcn_sched_barrier(0);
      // ---- stage issues (future tiles) ----
      if (q == 0) stageA(t + 1, 0);
      if (q == 1) { stageA(t + 1, 1); stageB(t + 2, 0); }
      if (q == 2) stageB(t + 2, 1);
      __builtin_amdgcn_sched_barrier(0);
      __builtin_amdgcn_s_barrier();
      __builtin_amdgcn_sched_barrier(0);
      // ---- MFMA cluster: quadrant q = m-frags {2q, 2q+1} x 4 n x 2 kk ----
      __builtin_amdgcn_s_setprio(1);
      #pragma unroll
      for (int kk = 0; kk < 2; ++kk)
        #pragma unroll
        for (int n = 0; n < 4; ++n) {
          acc[2*q+0][n] = __builtin_amdgcn_mfma_f32_16x16x32_bf16(am[0][kk], bfr[n][kk], acc[2*q+0][n], 0, 0, 0);
          acc[2*q+1][n] = __builtin_amdgcn_mfma_f32_16x16x32_bf16(am[1][kk], bfr[n][kk], acc[2*q+1][n], 0, 0, 0);
        }
      __builtin_amdgcn_s_setprio(0);
      __builtin_amdgcn_sched_barrier(0);
      if (q == 3 && t + 1 < NT) {
        if (t + 2 < NT) asm volatile("s_waitcnt vmcnt(4)" : : : "memory");
        else            asm volatile("s_waitcnt vmcnt(0)" : : : "memory");
      }
      __builtin_amdgcn_s_barrier();
      __builtin_amdgcn_sched_barrier(0);
    }
  }

  // ---- epilogue ----
  const int erow0 = tileM + wm * 128 + (lane >> 4) * 4;
  const int ecol0 = tileN + wn * 64 + lane15;
  #pragma unroll
  for (int m = 0; m < 8; ++m) {
    #pragma unroll
    for (int n = 0; n < 4; ++n) {
      #pragma unroll
      for (int r = 0; r < 4; ++r) {
        const int grow = erow0 + m * 16 + r;
        const int gcol = ecol0 + n * 16;
        const size_t idx = (size_t)grow * N + gcol;
        const float val = acc[m][n][r];
        if constexpr (EPI == 0) {
          outB[idx] = __float2bfloat16(val);
        } else if constexpr (EPI == 1) {
          float tt = fmaxf(val, 0.f);
          outB[idx] = __float2bfloat16(tt * tt);
        } else if constexpr (EPI == 2) {
          outF[idx] = addP[idx] + val;
        } else if constexpr (EPI == 3) {
          outB[idx] = __float2bfloat16(1.f / (1.f + __expf(-val)));
        } else {
          outF[idx] = addP[idx] + __bfloat162float(sigP[idx]) * val;
        }
      }
    }
  }
}

// ---------------- launch ----------------
extern "C" void kernel_launch(void* const* d_in, const int* in_sizes, int n_in,
                              void* d_out, int out_size, void* d_ws, size_t ws_size,
                              hipStream_t stream) {
  const float* x    = (const float*)d_in[0];
  const float* ln1w = (const float*)d_in[1];
  const float* ln1b = (const float*)d_in[2];
  const float* ln2w = (const float*)d_in[3];
  const float* ln2b = (const float*)d_in[4];
  const float* tmk  = (const float*)d_in[5];
  const float* tmv  = (const float*)d_in[6];
  const float* tmr  = (const float*)d_in[7];
  const float* td   = (const float*)d_in[8];
  const float* tf   = (const float*)d_in[9];
  const float* Wk   = (const float*)d_in[10];
  const float* Wv   = (const float*)d_in[11];
  const float* Wr   = (const float*)d_in[12];
  const float* Wo   = (const float*)d_in[13];
  const float* cmk  = (const float*)d_in[14];
  const float* cmr  = (const float*)d_in[15];
  const float* Wck  = (const float*)d_in[16];
  const float* Wcv  = (const float*)d_in[17];
  const float* Wcr  = (const float*)d_in[18];
  float* out = (float*)d_out;

  char* ws = (char*)d_ws;
  const size_t MB = 1ull << 20;
  bf16* R0 = (bf16*)(ws + 0 * MB);
  bf16* R1 = (bf16*)(ws + 32 * MB);
  bf16* R2 = (bf16*)(ws + 64 * MB);
  bf16* R3 = (bf16*)(ws + 96 * MB);
  bf16* R4 = (bf16*)(ws + 128 * MB);

  int S = (ws_size >= 256 * MB) ? 1 : (ws_size >= 192 * MB ? 2 : 4);
  const int FS = F_ / S;

  bf16* xk = R1, *xv = R2, *xr = R3;
  bf16* k_ = R4, *v_ = R1, *r_ = R2, *rwkv = R3;
  bf16* xk2 = R1, *xr2 = R2, *sig = R3, *kf = R4;

  const int gN2k = (BT_ / 256) * (D_ / 256);   // 32*8 = 256 blocks

  // --- TimeMix ---
  mix1f_kernel<<<BT_, 256, 0, stream>>>(x, ln1w, ln1b, tmk, tmv, tmr, xk, xv, xr);
  cvt_kernel<<<1024, 256, 0, stream>>>(Wk, R0, D_ * C_ / 4);
  gemm256<0><<<gN2k, 512, 0, stream>>>(xk, R0, D_, C_, nullptr, k_, nullptr, nullptr);
  cvt_kernel<<<1024, 256, 0, stream>>>(Wv, R0, D_ * C_ / 4);
  gemm256<0><<<gN2k, 512, 0, stream>>>(xv, R0, D_, C_, nullptr, v_, nullptr, nullptr);
  cvt_kernel<<<1024, 256, 0, stream>>>(Wr, R0, D_ * C_ / 4);
  gemm256<0><<<gN2k, 512, 0, stream>>>(xr, R0, D_, C_, nullptr, r_, nullptr, nullptr);
  wkv_kernel<<<B_ * D_ / 256, 256, 0, stream>>>(k_, v_, r_, td, tf, rwkv);
  cvt_kernel<<<1024, 256, 0, stream>>>(Wo, R0, C_ * D_ / 4);
  gemm256<2><<<gN2k, 512, 0, stream>>>(rwkv, R0, C_, D_, out, nullptr, x, nullptr);

  // --- ChannelMix ---
  mix2f_kernel<<<BT_, 256, 0, stream>>>(out, ln2w, ln2b, cmk, cmr, xk2, xr2);
  cvt_kernel<<<1024, 256, 0, stream>>>(Wcr, R0, C_ * C_ / 4);
  gemm256<3><<<gN2k, 512, 0, stream>>>(xr2, R0, C_, C_, nullptr, sig, nullptr, nullptr);
  for (int h = 0; h < S; ++h) {
    cvt_kernel<<<1024, 256, 0, stream>>>(Wck + (size_t)h * FS * C_, R0, FS * C_ / 4);
    gemm256<1><<<(BT_/256) * (FS/256), 512, 0, stream>>>(xk2, R0, FS, C_, nullptr, kf, nullptr, nullptr);
    packcvt_kernel<<<1024, 256, 0, stream>>>(Wcv, R0, C_, FS, F_, h * FS);
    gemm256<4><<<gN2k, 512, 0, stream>>>(kf, R0, C_, FS, out, nullptr, out, sig);
  }
}

// Round 4
// 1014.355 us; speedup vs baseline: 1.8326x; 1.3165x over previous
//
#include <hip/hip_runtime.h>
#include <hip/hip_bf16.h>

#define B_ 4
#define T_ 2048
#define C_ 2048
#define D_ 2048
#define F_ 8192
#define BT_ (B_*T_)
#define NCH 64
#define LCH 32

using bf16 = __hip_bfloat16;
typedef __attribute__((ext_vector_type(8))) short bf16x8;
typedef __attribute__((ext_vector_type(4))) float f32x4;

struct bf4 { bf16 a, b, c, d; };

__device__ __forceinline__ bf4 to_bf4(float x, float y, float z, float w) {
  bf4 r;
  r.a = __float2bfloat16(x); r.b = __float2bfloat16(y);
  r.c = __float2bfloat16(z); r.d = __float2bfloat16(w);
  return r;
}

// ---------------- fp32 -> bf16 conversion (contiguous) ----------------
__global__ __launch_bounds__(256) void cvt_kernel(const float* __restrict__ in,
                                                  bf16* __restrict__ out, int n4) {
  int i = blockIdx.x * blockDim.x + threadIdx.x;
  int stride = gridDim.x * blockDim.x;
  for (; i < n4; i += stride) {
    float4 v = ((const float4*)in)[i];
    ((bf4*)out)[i] = to_bf4(v.x, v.y, v.z, v.w);
  }
}

// ---------------- fp32 -> bf16 conversion of a column slice ----------------
__global__ __launch_bounds__(256) void packcvt_kernel(const float* __restrict__ in,
    bf16* __restrict__ out, int rows, int cols_out, int ld_in, int col0) {
  int n4 = rows * (cols_out >> 2);
  int c4 = cols_out >> 2;
  int i = blockIdx.x * blockDim.x + threadIdx.x;
  int stride = gridDim.x * blockDim.x;
  for (; i < n4; i += stride) {
    int r = i / c4;
    int j4 = i - r * c4;
    float4 v = *(const float4*)(in + (size_t)r * ld_in + col0 + j4 * 4);
    ((bf4*)out)[i] = to_bf4(v.x, v.y, v.z, v.w);
  }
}

// ---------------- block-wide reduce of 4 values (256 threads) ----------------
__device__ __forceinline__ void block_reduce4(float v[4], float out[4]) {
  #pragma unroll
  for (int i = 0; i < 4; ++i)
    #pragma unroll
    for (int off = 1; off < 64; off <<= 1)
      v[i] += __shfl_xor(v[i], off);
  __shared__ float red[4][4];
  int wave = threadIdx.x >> 6, lane = threadIdx.x & 63;
  if (lane == 0) {
    red[wave][0] = v[0]; red[wave][1] = v[1];
    red[wave][2] = v[2]; red[wave][3] = v[3];
  }
  __syncthreads();
  #pragma unroll
  for (int i = 0; i < 4; ++i)
    out[i] = red[0][i] + red[1][i] + red[2][i] + red[3][i];
}

// ---------------- fused LN + token-shift mix (TimeMix: 3 outputs) ----------------
__global__ __launch_bounds__(256) void mix1f_kernel(const float* __restrict__ x,
    const float* __restrict__ w, const float* __restrict__ b,
    const float* __restrict__ tmk, const float* __restrict__ tmv, const float* __restrict__ tmr,
    bf16* __restrict__ xk, bf16* __restrict__ xv, bf16* __restrict__ xr) {
  const int row = blockIdx.x;
  const int t = row & (T_ - 1);
  const bool hasPrev = (t != 0);
  const int tid = threadIdx.x;
  const float* xc = x + (size_t)row * C_;
  const float* xp = xc - C_;
  float c[8], p[8];
  *(float4*)&c[0] = *(const float4*)(xc + tid * 4);
  *(float4*)&c[4] = *(const float4*)(xc + tid * 4 + 1024);
  if (hasPrev) {
    *(float4*)&p[0] = *(const float4*)(xp + tid * 4);
    *(float4*)&p[4] = *(const float4*)(xp + tid * 4 + 1024);
  } else {
    #pragma unroll
    for (int j = 0; j < 8; ++j) p[j] = 0.f;
  }
  float v[4] = {0.f, 0.f, 0.f, 0.f}, tot[4];
  #pragma unroll
  for (int j = 0; j < 8; ++j) {
    v[0] += c[j]; v[1] += c[j] * c[j];
    v[2] += p[j]; v[3] += p[j] * p[j];
  }
  block_reduce4(v, tot);
  const float muc = tot[0] * (1.f / C_);
  const float rsc = rsqrtf(tot[1] * (1.f / C_) - muc * muc + 1e-5f);
  const float mup = tot[2] * (1.f / C_);
  const float rsp = rsqrtf(tot[3] * (1.f / C_) - mup * mup + 1e-5f);
  float wv[8], bv[8], mk[8], mv[8], mr[8];
  #pragma unroll
  for (int half = 0; half < 2; ++half) {
    int i = tid * 4 + half * 1024;
    *(float4*)&wv[half*4] = *(const float4*)(w + i);
    *(float4*)&bv[half*4] = *(const float4*)(b + i);
    *(float4*)&mk[half*4] = *(const float4*)(tmk + i);
    *(float4*)&mv[half*4] = *(const float4*)(tmv + i);
    *(float4*)&mr[half*4] = *(const float4*)(tmr + i);
  }
  float ok[8], ov[8], orr[8];
  #pragma unroll
  for (int j = 0; j < 8; ++j) {
    float h  = (c[j] - muc) * rsc * wv[j] + bv[j];
    float hh = hasPrev ? ((p[j] - mup) * rsp * wv[j] + bv[j]) : 0.f;
    ok[j]  = hh + mk[j] * (h - hh);
    ov[j]  = hh + mv[j] * (h - hh);
    orr[j] = hh + mr[j] * (h - hh);
  }
  size_t ro = (size_t)row * C_;
  #pragma unroll
  for (int half = 0; half < 2; ++half) {
    int i = tid * 4 + half * 1024;
    *(bf4*)(xk + ro + i) = to_bf4(ok[half*4], ok[half*4+1], ok[half*4+2], ok[half*4+3]);
    *(bf4*)(xv + ro + i) = to_bf4(ov[half*4], ov[half*4+1], ov[half*4+2], ov[half*4+3]);
    *(bf4*)(xr + ro + i) = to_bf4(orr[half*4], orr[half*4+1], orr[half*4+2], orr[half*4+3]);
  }
}

// ---------------- fused LN + token-shift mix (ChannelMix: 2 outputs) ----------------
__global__ __launch_bounds__(256) void mix2f_kernel(const float* __restrict__ x,
    const float* __restrict__ w, const float* __restrict__ b,
    const float* __restrict__ cmk, const float* __restrict__ cmr,
    bf16* __restrict__ xk2, bf16* __restrict__ xr2) {
  const int row = blockIdx.x;
  const int t = row & (T_ - 1);
  const bool hasPrev = (t != 0);
  const int tid = threadIdx.x;
  const float* xc = x + (size_t)row * C_;
  const float* xp = xc - C_;
  float c[8], p[8];
  *(float4*)&c[0] = *(const float4*)(xc + tid * 4);
  *(float4*)&c[4] = *(const float4*)(xc + tid * 4 + 1024);
  if (hasPrev) {
    *(float4*)&p[0] = *(const float4*)(xp + tid * 4);
    *(float4*)&p[4] = *(const float4*)(xp + tid * 4 + 1024);
  } else {
    #pragma unroll
    for (int j = 0; j < 8; ++j) p[j] = 0.f;
  }
  float v[4] = {0.f, 0.f, 0.f, 0.f}, tot[4];
  #pragma unroll
  for (int j = 0; j < 8; ++j) {
    v[0] += c[j]; v[1] += c[j] * c[j];
    v[2] += p[j]; v[3] += p[j] * p[j];
  }
  block_reduce4(v, tot);
  const float muc = tot[0] * (1.f / C_);
  const float rsc = rsqrtf(tot[1] * (1.f / C_) - muc * muc + 1e-5f);
  const float mup = tot[2] * (1.f / C_);
  const float rsp = rsqrtf(tot[3] * (1.f / C_) - mup * mup + 1e-5f);
  float wv[8], bv[8], mk[8], mr[8];
  #pragma unroll
  for (int half = 0; half < 2; ++half) {
    int i = tid * 4 + half * 1024;
    *(float4*)&wv[half*4] = *(const float4*)(w + i);
    *(float4*)&bv[half*4] = *(const float4*)(b + i);
    *(float4*)&mk[half*4] = *(const float4*)(cmk + i);
    *(float4*)&mr[half*4] = *(const float4*)(cmr + i);
  }
  float ok[8], orr[8];
  #pragma unroll
  for (int j = 0; j < 8; ++j) {
    float h  = (c[j] - muc) * rsc * wv[j] + bv[j];
    float hh = hasPrev ? ((p[j] - mup) * rsp * wv[j] + bv[j]) : 0.f;
    ok[j]  = hh + mk[j] * (h - hh);
    orr[j] = hh + mr[j] * (h - hh);
  }
  size_t ro = (size_t)row * C_;
  #pragma unroll
  for (int half = 0; half < 2; ++half) {
    int i = tid * 4 + half * 1024;
    *(bf4*)(xk2 + ro + i) = to_bf4(ok[half*4], ok[half*4+1], ok[half*4+2], ok[half*4+3]);
    *(bf4*)(xr2 + ro + i) = to_bf4(orr[half*4], orr[half*4+1], orr[half*4+2], orr[half*4+3]);
  }
}

// ================= chunk-parallel WKV =================
// Un-normalized recurrence A' = e^w A + e^k v, B' = e^w B + e^k, carried as
// (aa,bb,pp): A = aa*e^pp. T split into NCH chunks of LCH.
// pass1: per-(b,d,chunk) local sums.  pass2: per-(b,d) exclusive prefix scan
// over chunks (in-place).  pass3: per-(b,d,chunk) replay emitting sigmoid(r)*out.

__global__ __launch_bounds__(256) void wkv_pass1(
    const bf16* __restrict__ kp, const bf16* __restrict__ vp,
    const float* __restrict__ td,
    float* __restrict__ sA, float* __restrict__ sB, float* __restrict__ sP) {
  const int g = blockIdx.x * 256 + threadIdx.x;   // b(2) | c(6) | d(11)
  const int d = g & (D_ - 1);
  const int c = (g >> 11) & (NCH - 1);
  const int b = g >> 17;
  const float w = -__expf(td[d]);
  const size_t base = ((size_t)b * T_ + c * LCH) * D_ + d;
  float aa = 0.f, bb = 0.f, pp = -1e38f;
  #pragma unroll 4
  for (int j = 0; j < LCH; ++j) {
    float kt = __bfloat162float(kp[base + (size_t)j * D_]);
    float vt = __bfloat162float(vp[base + (size_t)j * D_]);
    float ww2 = pp + w;
    float p2 = fmaxf(ww2, kt);
    float e1 = __expf(ww2 - p2), e2 = __expf(kt - p2);
    aa = e1 * aa + e2 * vt;
    bb = e1 * bb + e2;
    pp = p2;
  }
  const int sidx = ((b * NCH + c) << 11) + d;
  sA[sidx] = aa; sB[sidx] = bb; sP[sidx] = pp;
}

__global__ __launch_bounds__(256) void wkv_pass2(
    const float* __restrict__ td,
    float* __restrict__ sA, float* __restrict__ sB, float* __restrict__ sP) {
  const int g = blockIdx.x * 256 + threadIdx.x;   // b(2) | d(11)
  const int d = g & (D_ - 1);
  const int b = g >> 11;
  const float wL = -__expf(td[d]) * (float)LCH;
  float aa = 0.f, bb = 0.f, pp = -1e38f;
  for (int c = 0; c < NCH; ++c) {
    const int sidx = ((b * NCH + c) << 11) + d;
    float la = sA[sidx], lb = sB[sidx], lp = sP[sidx];
    sA[sidx] = aa; sB[sidx] = bb; sP[sidx] = pp;   // exclusive prefix
    float ww2 = pp + wL;
    float q = fmaxf(ww2, lp);
    float e1 = __expf(ww2 - q), e2 = __expf(lp - q);
    aa = e1 * aa + e2 * la;
    bb = e1 * bb + e2 * lb;
    pp = q;
  }
}

__global__ __launch_bounds__(256) void wkv_pass3(
    const bf16* __restrict__ kp, const bf16* __restrict__ vp, const bf16* __restrict__ rp,
    const float* __restrict__ td, const float* __restrict__ tfp,
    const float* __restrict__ sA, const float* __restrict__ sB, const float* __restrict__ sP,
    bf16* __restrict__ rwkv) {
  const int g = blockIdx.x * 256 + threadIdx.x;
  const int d = g & (D_ - 1);
  const int c = (g >> 11) & (NCH - 1);
  const int b = g >> 17;
  const float w = -__expf(td[d]);
  const float u = tfp[d];
  const int sidx = ((b * NCH + c) << 11) + d;
  float aa = sA[sidx], bb = sB[sidx], pp = sP[sidx];
  const size_t base = ((size_t)b * T_ + c * LCH) * D_ + d;
  #pragma unroll 4
  for (int j = 0; j < LCH; ++j) {
    float kt = __bfloat162float(kp[base + (size_t)j * D_]);
    float vt = __bfloat162float(vp[base + (size_t)j * D_]);
    float rt = __bfloat162float(rp[base + (size_t)j * D_]);
    float ww = u + kt;
    float p = fmaxf(pp, ww);
    float e1 = __expf(pp - p);
    float e2 = __expf(ww - p);
    float outv = (e1 * aa + e2 * vt) / (e1 * bb + e2);
    float sr = 1.f / (1.f + __expf(-rt));
    rwkv[base + (size_t)j * D_] = __float2bfloat16(sr * outv);
    float ww2 = pp + w;
    float p2 = fmaxf(ww2, kt);
    float e1b = __expf(ww2 - p2);
    float e2b = __expf(kt - p2);
    aa = e1b * aa + e2b * vt;
    bb = e1b * bb + e2b;
    pp = p2;
  }
}

// ================= 256x256 8-phase bf16 MFMA GEMM =================
// C[M][N] = A[M][K] * Bt[N][K]^T.  512 threads = 8 waves (2M x 4N).
// EPI: 0 bf16, 1 relu^2 bf16, 2 fp32 add-res, 3 sigmoid bf16, 4 add-res+sig-gate.
template<int EPI>
__global__ __launch_bounds__(512, 2) void gemm256(
    const bf16* __restrict__ A, const bf16* __restrict__ Bt,
    int N, int K,
    float* __restrict__ outF, bf16* __restrict__ outB,
    const float* __restrict__ addP, const bf16* __restrict__ sigP) {
  __shared__ alignas(16) char lds[131072];   // A: [0,64K) , B: [64K,128K)
  const int tid = threadIdx.x;
  const int wid = tid >> 6, lane = tid & 63;
  const int wm = wid >> 2, wn = wid & 3;

  const int nwg = gridDim.x;
  const int id = blockIdx.x;
  const int cpx = nwg >> 3;
  const int sid = (id & 7) * cpx + (id >> 3);
  const int nx = N >> 8;
  const int by = sid / nx, bx = sid - by * nx;
  const int tileM = by * 256, tileN = bx * 256;

  const int NT = K >> 6;

  const int srow_lo = wid * 8 + (lane >> 3);
  const int scel = ((lane & 7) ^ (lane >> 3)) << 3;

  auto stageA = [&](int tau, int h) {
    if (tau >= NT) return;
    const bf16* gb = A + (size_t)(tileM + h * 128) * K + tau * 64;
    char* lb = lds + (tau & 1) * 32768 + h * 16384 + wid * 1024;
    #pragma unroll
    for (int j = 0; j < 2; ++j) {
      const bf16* g = gb + (size_t)(srow_lo + j * 64) * K + scel;
      __builtin_amdgcn_global_load_lds(
          (const __attribute__((address_space(1))) void*)g,
          (__attribute__((address_space(3))) void*)(lb + j * 8192), 16, 0, 0);
    }
  };
  auto stageB = [&](int tau, int h) {
    if (tau >= NT) return;
    const bf16* gb = Bt + (size_t)(tileN + h * 128) * K + tau * 64;
    char* lb = lds + 65536 + (tau & 1) * 32768 + h * 16384 + wid * 1024;
    #pragma unroll
    for (int j = 0; j < 2; ++j) {
      const bf16* g = gb + (size_t)(srow_lo + j * 64) * K + scel;
      __builtin_amdgcn_global_load_lds(
          (const __attribute__((address_space(1))) void*)g,
          (__attribute__((address_space(3))) void*)(lb + j * 8192), 16, 0, 0);
    }
  };

  const int lane15 = lane & 15;
  const int kswz0 = ((lane >> 4) * 16) ^ ((lane & 7) << 4);
  const int aBase = (wm * 128 + lane15) * 128;
  const int bBase = (wn * 64 + lane15) * 128;

  f32x4 acc[8][4] = {};

  stageB(0, 0); stageB(0, 1); stageA(0, 0); stageA(0, 1); stageB(1, 0); stageB(1, 1);
  asm volatile("s_waitcnt vmcnt(4)" : : : "memory");
  __builtin_amdgcn_s_barrier();
  __builtin_amdgcn_sched_barrier(0);

  for (int t = 0; t < NT; ++t) {
    const char* Ab = lds + (t & 1) * 32768;
    const char* Bb = lds + 65536 + (t & 1) * 32768;
    bf16x8 bfr[4][2];
    #pragma unroll
    for (int q = 0; q < 4; ++q) {
      if (q == 0) {
        #pragma unroll
        for (int n = 0; n < 4; ++n) {
          bfr[n][0] = *(const bf16x8*)(Bb + bBase + n * 2048 + kswz0);
          bfr[n][1] = *(const bf16x8*)(Bb + bBase + n * 2048 + (kswz0 ^ 64));
        }
      }
      bf16x8 am[2][2];
      #pragma unroll
      for (int mm = 0; mm < 2; ++mm) {
        am[mm][0] = *(const bf16x8*)(Ab + aBase + q * 4096 + mm * 2048 + kswz0);
        am[mm][1] = *(const bf16x8*)(Ab + aBase + q * 4096 + mm * 2048 + (kswz0 ^ 64));
      }
      __builtin_amdgcn_sched_barrier(0);
      if (q == 0) stageA(t + 1, 0);
      if (q == 1) { stageA(t + 1, 1); stageB(t + 2, 0); }
      if (q == 2) stageB(t + 2, 1);
      __builtin_amdgcn_sched_barrier(0);
      __builtin_amdgcn_s_barrier();
      __builtin_amdgcn_sched_barrier(0);
      __builtin_amdgcn_s_setprio(1);
      #pragma unroll
      for (int kk = 0; kk < 2; ++kk)
        #pragma unroll
        for (int n = 0; n < 4; ++n) {
          acc[2*q+0][n] = __builtin_amdgcn_mfma_f32_16x16x32_bf16(am[0][kk], bfr[n][kk], acc[2*q+0][n], 0, 0, 0);
          acc[2*q+1][n] = __builtin_amdgcn_mfma_f32_16x16x32_bf16(am[1][kk], bfr[n][kk], acc[2*q+1][n], 0, 0, 0);
        }
      __builtin_amdgcn_s_setprio(0);
      __builtin_amdgcn_sched_barrier(0);
      if (q == 3 && t + 1 < NT) {
        if (t + 2 < NT) asm volatile("s_waitcnt vmcnt(4)" : : : "memory");
        else            asm volatile("s_waitcnt vmcnt(0)" : : : "memory");
      }
      __builtin_amdgcn_s_barrier();
      __builtin_amdgcn_sched_barrier(0);
    }
  }

  const int erow0 = tileM + wm * 128 + (lane >> 4) * 4;
  const int ecol0 = tileN + wn * 64 + lane15;
  #pragma unroll
  for (int m = 0; m < 8; ++m) {
    #pragma unroll
    for (int n = 0; n < 4; ++n) {
      #pragma unroll
      for (int r = 0; r < 4; ++r) {
        const int grow = erow0 + m * 16 + r;
        const int gcol = ecol0 + n * 16;
        const size_t idx = (size_t)grow * N + gcol;
        const float val = acc[m][n][r];
        if constexpr (EPI == 0) {
          outB[idx] = __float2bfloat16(val);
        } else if constexpr (EPI == 1) {
          float tt = fmaxf(val, 0.f);
          outB[idx] = __float2bfloat16(tt * tt);
        } else if constexpr (EPI == 2) {
          outF[idx] = addP[idx] + val;
        } else if constexpr (EPI == 3) {
          outB[idx] = __float2bfloat16(1.f / (1.f + __expf(-val)));
        } else {
          outF[idx] = addP[idx] + __bfloat162float(sigP[idx]) * val;
        }
      }
    }
  }
}

// ---------------- launch ----------------
extern "C" void kernel_launch(void* const* d_in, const int* in_sizes, int n_in,
                              void* d_out, int out_size, void* d_ws, size_t ws_size,
                              hipStream_t stream) {
  const float* x    = (const float*)d_in[0];
  const float* ln1w = (const float*)d_in[1];
  const float* ln1b = (const float*)d_in[2];
  const float* ln2w = (const float*)d_in[3];
  const float* ln2b = (const float*)d_in[4];
  const float* tmk  = (const float*)d_in[5];
  const float* tmv  = (const float*)d_in[6];
  const float* tmr  = (const float*)d_in[7];
  const float* td   = (const float*)d_in[8];
  const float* tf   = (const float*)d_in[9];
  const float* Wk   = (const float*)d_in[10];
  const float* Wv   = (const float*)d_in[11];
  const float* Wr   = (const float*)d_in[12];
  const float* Wo   = (const float*)d_in[13];
  const float* cmk  = (const float*)d_in[14];
  const float* cmr  = (const float*)d_in[15];
  const float* Wck  = (const float*)d_in[16];
  const float* Wcv  = (const float*)d_in[17];
  const float* Wcr  = (const float*)d_in[18];
  float* out = (float*)d_out;

  char* ws = (char*)d_ws;
  const size_t MB = 1ull << 20;
  bf16* R0 = (bf16*)(ws + 0 * MB);
  bf16* R1 = (bf16*)(ws + 32 * MB);
  bf16* R2 = (bf16*)(ws + 64 * MB);
  bf16* R3 = (bf16*)(ws + 96 * MB);
  bf16* R4 = (bf16*)(ws + 128 * MB);

  int S = (ws_size >= 256 * MB) ? 1 : (ws_size >= 192 * MB ? 2 : 4);
  const int FS = F_ / S;

  bf16* xk = R1, *xv = R2, *xr = R3;
  bf16* k_ = R4, *v_ = R1, *r_ = R2, *rwkv = R3;
  bf16* xk2 = R1, *xr2 = R2, *sig = R3, *kf = R4;

  // WKV chunk-state arrays live in R0 (dead during wkv; Wo cvt comes after)
  float* sA = (float*)R0;
  float* sB = sA + (size_t)B_ * NCH * D_;
  float* sP = sB + (size_t)B_ * NCH * D_;

  const int gN2k = (BT_ / 256) * (D_ / 256);   // 256 blocks

  // --- TimeMix ---
  mix1f_kernel<<<BT_, 256, 0, stream>>>(x, ln1w, ln1b, tmk, tmv, tmr, xk, xv, xr);
  cvt_kernel<<<1024, 256, 0, stream>>>(Wk, R0, D_ * C_ / 4);
  gemm256<0><<<gN2k, 512, 0, stream>>>(xk, R0, D_, C_, nullptr, k_, nullptr, nullptr);
  cvt_kernel<<<1024, 256, 0, stream>>>(Wv, R0, D_ * C_ / 4);
  gemm256<0><<<gN2k, 512, 0, stream>>>(xv, R0, D_, C_, nullptr, v_, nullptr, nullptr);
  cvt_kernel<<<1024, 256, 0, stream>>>(Wr, R0, D_ * C_ / 4);
  gemm256<0><<<gN2k, 512, 0, stream>>>(xr, R0, D_, C_, nullptr, r_, nullptr, nullptr);
  wkv_pass1<<<B_ * NCH * D_ / 256, 256, 0, stream>>>(k_, v_, td, sA, sB, sP);
  wkv_pass2<<<B_ * D_ / 256, 256, 0, stream>>>(td, sA, sB, sP);
  wkv_pass3<<<B_ * NCH * D_ / 256, 256, 0, stream>>>(k_, v_, r_, td, tf, sA, sB, sP, rwkv);
  cvt_kernel<<<1024, 256, 0, stream>>>(Wo, R0, C_ * D_ / 4);
  gemm256<2><<<gN2k, 512, 0, stream>>>(rwkv, R0, C_, D_, out, nullptr, x, nullptr);

  // --- ChannelMix ---
  mix2f_kernel<<<BT_, 256, 0, stream>>>(out, ln2w, ln2b, cmk, cmr, xk2, xr2);
  cvt_kernel<<<1024, 256, 0, stream>>>(Wcr, R0, C_ * C_ / 4);
  gemm256<3><<<gN2k, 512, 0, stream>>>(xr2, R0, C_, C_, nullptr, sig, nullptr, nullptr);
  for (int h = 0; h < S; ++h) {
    cvt_kernel<<<1024, 256, 0, stream>>>(Wck + (size_t)h * FS * C_, R0, FS * C_ / 4);
    gemm256<1><<<(BT_/256) * (FS/256), 512, 0, stream>>>(xk2, R0, FS, C_, nullptr, kf, nullptr, nullptr);
    packcvt_kernel<<<1024, 256, 0, stream>>>(Wcv, R0, C_, FS, F_, h * FS);
    gemm256<4><<<gN2k, 512, 0, stream>>>(kf, R0, C_, FS, out, nullptr, out, sig);
  }
}

// Round 5
// 1009.098 us; speedup vs baseline: 1.8421x; 1.0052x over previous
//
#include <hip/hip_runtime.h>
#include <hip/hip_bf16.h>

#define B_ 4
#define T_ 2048
#define C_ 2048
#define D_ 2048
#define F_ 8192
#define BT_ (B_*T_)
#define NCH 64
#define LCH 32

using bf16 = __hip_bfloat16;
typedef __attribute__((ext_vector_type(8))) short bf16x8;
typedef __attribute__((ext_vector_type(4))) float f32x4;

struct bf4 { bf16 a, b, c, d; };

__device__ __forceinline__ bf4 to_bf4(float x, float y, float z, float w) {
  bf4 r;
  r.a = __float2bfloat16(x); r.b = __float2bfloat16(y);
  r.c = __float2bfloat16(z); r.d = __float2bfloat16(w);
  return r;
}

// ---------------- fp32 -> bf16 conversion (contiguous) ----------------
__global__ __launch_bounds__(256) void cvt_kernel(const float* __restrict__ in,
                                                  bf16* __restrict__ out, int n4) {
  int i = blockIdx.x * blockDim.x + threadIdx.x;
  int stride = gridDim.x * blockDim.x;
  for (; i < n4; i += stride) {
    float4 v = ((const float4*)in)[i];
    ((bf4*)out)[i] = to_bf4(v.x, v.y, v.z, v.w);
  }
}

// ---------------- fp32 -> bf16 conversion of a column slice ----------------
__global__ __launch_bounds__(256) void packcvt_kernel(const float* __restrict__ in,
    bf16* __restrict__ out, int rows, int cols_out, int ld_in, int col0) {
  int n4 = rows * (cols_out >> 2);
  int c4 = cols_out >> 2;
  int i = blockIdx.x * blockDim.x + threadIdx.x;
  int stride = gridDim.x * blockDim.x;
  for (; i < n4; i += stride) {
    int r = i / c4;
    int j4 = i - r * c4;
    float4 v = *(const float4*)(in + (size_t)r * ld_in + col0 + j4 * 4);
    ((bf4*)out)[i] = to_bf4(v.x, v.y, v.z, v.w);
  }
}

// ---------------- block-wide reduce of 4 values (256 threads) ----------------
__device__ __forceinline__ void block_reduce4(float v[4], float out[4]) {
  #pragma unroll
  for (int i = 0; i < 4; ++i)
    #pragma unroll
    for (int off = 1; off < 64; off <<= 1)
      v[i] += __shfl_xor(v[i], off);
  __shared__ float red[4][4];
  int wave = threadIdx.x >> 6, lane = threadIdx.x & 63;
  if (lane == 0) {
    red[wave][0] = v[0]; red[wave][1] = v[1];
    red[wave][2] = v[2]; red[wave][3] = v[3];
  }
  __syncthreads();
  #pragma unroll
  for (int i = 0; i < 4; ++i)
    out[i] = red[0][i] + red[1][i] + red[2][i] + red[3][i];
}

// ---------------- fused LN + token-shift mix (TimeMix: 3 outputs) ----------------
__global__ __launch_bounds__(256) void mix1f_kernel(const float* __restrict__ x,
    const float* __restrict__ w, const float* __restrict__ b,
    const float* __restrict__ tmk, const float* __restrict__ tmv, const float* __restrict__ tmr,
    bf16* __restrict__ xk, bf16* __restrict__ xv, bf16* __restrict__ xr) {
  const int row = blockIdx.x;
  const int t = row & (T_ - 1);
  const bool hasPrev = (t != 0);
  const int tid = threadIdx.x;
  const float* xc = x + (size_t)row * C_;
  const float* xp = xc - C_;
  float c[8], p[8];
  *(float4*)&c[0] = *(const float4*)(xc + tid * 4);
  *(float4*)&c[4] = *(const float4*)(xc + tid * 4 + 1024);
  if (hasPrev) {
    *(float4*)&p[0] = *(const float4*)(xp + tid * 4);
    *(float4*)&p[4] = *(const float4*)(xp + tid * 4 + 1024);
  } else {
    #pragma unroll
    for (int j = 0; j < 8; ++j) p[j] = 0.f;
  }
  float v[4] = {0.f, 0.f, 0.f, 0.f}, tot[4];
  #pragma unroll
  for (int j = 0; j < 8; ++j) {
    v[0] += c[j]; v[1] += c[j] * c[j];
    v[2] += p[j]; v[3] += p[j] * p[j];
  }
  block_reduce4(v, tot);
  const float muc = tot[0] * (1.f / C_);
  const float rsc = rsqrtf(tot[1] * (1.f / C_) - muc * muc + 1e-5f);
  const float mup = tot[2] * (1.f / C_);
  const float rsp = rsqrtf(tot[3] * (1.f / C_) - mup * mup + 1e-5f);
  float wv[8], bv[8], mk[8], mv[8], mr[8];
  #pragma unroll
  for (int half = 0; half < 2; ++half) {
    int i = tid * 4 + half * 1024;
    *(float4*)&wv[half*4] = *(const float4*)(w + i);
    *(float4*)&bv[half*4] = *(const float4*)(b + i);
    *(float4*)&mk[half*4] = *(const float4*)(tmk + i);
    *(float4*)&mv[half*4] = *(const float4*)(tmv + i);
    *(float4*)&mr[half*4] = *(const float4*)(tmr + i);
  }
  float ok[8], ov[8], orr[8];
  #pragma unroll
  for (int j = 0; j < 8; ++j) {
    float h  = (c[j] - muc) * rsc * wv[j] + bv[j];
    float hh = hasPrev ? ((p[j] - mup) * rsp * wv[j] + bv[j]) : 0.f;
    ok[j]  = hh + mk[j] * (h - hh);
    ov[j]  = hh + mv[j] * (h - hh);
    orr[j] = hh + mr[j] * (h - hh);
  }
  size_t ro = (size_t)row * C_;
  #pragma unroll
  for (int half = 0; half < 2; ++half) {
    int i = tid * 4 + half * 1024;
    *(bf4*)(xk + ro + i) = to_bf4(ok[half*4], ok[half*4+1], ok[half*4+2], ok[half*4+3]);
    *(bf4*)(xv + ro + i) = to_bf4(ov[half*4], ov[half*4+1], ov[half*4+2], ov[half*4+3]);
    *(bf4*)(xr + ro + i) = to_bf4(orr[half*4], orr[half*4+1], orr[half*4+2], orr[half*4+3]);
  }
}

// ---------------- fused LN + token-shift mix (ChannelMix: 2 outputs) ----------------
__global__ __launch_bounds__(256) void mix2f_kernel(const float* __restrict__ x,
    const float* __restrict__ w, const float* __restrict__ b,
    const float* __restrict__ cmk, const float* __restrict__ cmr,
    bf16* __restrict__ xk2, bf16* __restrict__ xr2) {
  const int row = blockIdx.x;
  const int t = row & (T_ - 1);
  const bool hasPrev = (t != 0);
  const int tid = threadIdx.x;
  const float* xc = x + (size_t)row * C_;
  const float* xp = xc - C_;
  float c[8], p[8];
  *(float4*)&c[0] = *(const float4*)(xc + tid * 4);
  *(float4*)&c[4] = *(const float4*)(xc + tid * 4 + 1024);
  if (hasPrev) {
    *(float4*)&p[0] = *(const float4*)(xp + tid * 4);
    *(float4*)&p[4] = *(const float4*)(xp + tid * 4 + 1024);
  } else {
    #pragma unroll
    for (int j = 0; j < 8; ++j) p[j] = 0.f;
  }
  float v[4] = {0.f, 0.f, 0.f, 0.f}, tot[4];
  #pragma unroll
  for (int j = 0; j < 8; ++j) {
    v[0] += c[j]; v[1] += c[j] * c[j];
    v[2] += p[j]; v[3] += p[j] * p[j];
  }
  block_reduce4(v, tot);
  const float muc = tot[0] * (1.f / C_);
  const float rsc = rsqrtf(tot[1] * (1.f / C_) - muc * muc + 1e-5f);
  const float mup = tot[2] * (1.f / C_);
  const float rsp = rsqrtf(tot[3] * (1.f / C_) - mup * mup + 1e-5f);
  float wv[8], bv[8], mk[8], mr[8];
  #pragma unroll
  for (int half = 0; half < 2; ++half) {
    int i = tid * 4 + half * 1024;
    *(float4*)&wv[half*4] = *(const float4*)(w + i);
    *(float4*)&bv[half*4] = *(const float4*)(b + i);
    *(float4*)&mk[half*4] = *(const float4*)(cmk + i);
    *(float4*)&mr[half*4] = *(const float4*)(cmr + i);
  }
  float ok[8], orr[8];
  #pragma unroll
  for (int j = 0; j < 8; ++j) {
    float h  = (c[j] - muc) * rsc * wv[j] + bv[j];
    float hh = hasPrev ? ((p[j] - mup) * rsp * wv[j] + bv[j]) : 0.f;
    ok[j]  = hh + mk[j] * (h - hh);
    orr[j] = hh + mr[j] * (h - hh);
  }
  size_t ro = (size_t)row * C_;
  #pragma unroll
  for (int half = 0; half < 2; ++half) {
    int i = tid * 4 + half * 1024;
    *(bf4*)(xk2 + ro + i) = to_bf4(ok[half*4], ok[half*4+1], ok[half*4+2], ok[half*4+3]);
    *(bf4*)(xr2 + ro + i) = to_bf4(orr[half*4], orr[half*4+1], orr[half*4+2], orr[half*4+3]);
  }
}

// ================= chunk-parallel WKV =================
__global__ __launch_bounds__(256) void wkv_pass1(
    const bf16* __restrict__ kp, const bf16* __restrict__ vp,
    const float* __restrict__ td,
    float* __restrict__ sA, float* __restrict__ sB, float* __restrict__ sP) {
  const int g = blockIdx.x * 256 + threadIdx.x;   // b(2) | c(6) | d(11)
  const int d = g & (D_ - 1);
  const int c = (g >> 11) & (NCH - 1);
  const int b = g >> 17;
  const float w = -__expf(td[d]);
  const size_t base = ((size_t)b * T_ + c * LCH) * D_ + d;
  float aa = 0.f, bb = 0.f, pp = -1e38f;
  #pragma unroll 4
  for (int j = 0; j < LCH; ++j) {
    float kt = __bfloat162float(kp[base + (size_t)j * D_]);
    float vt = __bfloat162float(vp[base + (size_t)j * D_]);
    float ww2 = pp + w;
    float p2 = fmaxf(ww2, kt);
    float e1 = __expf(ww2 - p2), e2 = __expf(kt - p2);
    aa = e1 * aa + e2 * vt;
    bb = e1 * bb + e2;
    pp = p2;
  }
  const int sidx = ((b * NCH + c) << 11) + d;
  sA[sidx] = aa; sB[sidx] = bb; sP[sidx] = pp;
}

__global__ __launch_bounds__(256) void wkv_pass2(
    const float* __restrict__ td,
    float* __restrict__ sA, float* __restrict__ sB, float* __restrict__ sP) {
  const int g = blockIdx.x * 256 + threadIdx.x;   // b(2) | d(11)
  const int d = g & (D_ - 1);
  const int b = g >> 11;
  const float wL = -__expf(td[d]) * (float)LCH;
  float aa = 0.f, bb = 0.f, pp = -1e38f;
  for (int c = 0; c < NCH; ++c) {
    const int sidx = ((b * NCH + c) << 11) + d;
    float la = sA[sidx], lb = sB[sidx], lp = sP[sidx];
    sA[sidx] = aa; sB[sidx] = bb; sP[sidx] = pp;   // exclusive prefix
    float ww2 = pp + wL;
    float q = fmaxf(ww2, lp);
    float e1 = __expf(ww2 - q), e2 = __expf(lp - q);
    aa = e1 * aa + e2 * la;
    bb = e1 * bb + e2 * lb;
    pp = q;
  }
}

__global__ __launch_bounds__(256) void wkv_pass3(
    const bf16* __restrict__ kp, const bf16* __restrict__ vp, const bf16* __restrict__ rp,
    const float* __restrict__ td, const float* __restrict__ tfp,
    const float* __restrict__ sA, const float* __restrict__ sB, const float* __restrict__ sP,
    bf16* __restrict__ rwkv) {
  const int g = blockIdx.x * 256 + threadIdx.x;
  const int d = g & (D_ - 1);
  const int c = (g >> 11) & (NCH - 1);
  const int b = g >> 17;
  const float w = -__expf(td[d]);
  const float u = tfp[d];
  const int sidx = ((b * NCH + c) << 11) + d;
  float aa = sA[sidx], bb = sB[sidx], pp = sP[sidx];
  const size_t base = ((size_t)b * T_ + c * LCH) * D_ + d;
  #pragma unroll 4
  for (int j = 0; j < LCH; ++j) {
    float kt = __bfloat162float(kp[base + (size_t)j * D_]);
    float vt = __bfloat162float(vp[base + (size_t)j * D_]);
    float rt = __bfloat162float(rp[base + (size_t)j * D_]);
    float ww = u + kt;
    float p = fmaxf(pp, ww);
    float e1 = __expf(pp - p);
    float e2 = __expf(ww - p);
    float outv = (e1 * aa + e2 * vt) / (e1 * bb + e2);
    float sr = 1.f / (1.f + __expf(-rt));
    rwkv[base + (size_t)j * D_] = __float2bfloat16(sr * outv);
    float ww2 = pp + w;
    float p2 = fmaxf(ww2, kt);
    float e1b = __expf(ww2 - p2);
    float e2b = __expf(kt - p2);
    aa = e1b * aa + e2b * vt;
    bb = e1b * bb + e2b;
    pp = p2;
  }
}

// ================= 256x256 8-phase bf16 MFMA GEMM =================
// C[M][N] = A[M][K] * Bt[N][K]^T.  512 threads = 8 waves (2M x 4N).
// Staging addresses hoisted into persistent per-lane pointers (+64/tile);
// LDS dest parity is a uniform SALU term.  Schedule identical to round 4.
template<int EPI>
__global__ __launch_bounds__(512, 2) void gemm256(
    const bf16* __restrict__ A, const bf16* __restrict__ Bt,
    int N, int K,
    float* __restrict__ outF, bf16* __restrict__ outB,
    const float* __restrict__ addP, const bf16* __restrict__ sigP) {
  __shared__ alignas(16) char lds[131072];   // A: [0,64K) , B: [64K,128K)
  const int tid = threadIdx.x;
  const int wid = tid >> 6, lane = tid & 63;
  const int wm = wid >> 2, wn = wid & 3;

  const int nwg = gridDim.x;
  const int id = blockIdx.x;
  const int cpx = nwg >> 3;
  const int sid = (id & 7) * cpx + (id >> 3);
  const int nx = N >> 8;
  const int by = sid / nx, bx = sid - by * nx;
  const int tileM = by * 256, tileN = bx * 256;

  const int NT = K >> 6;

  const int srow_lo = wid * 8 + (lane >> 3);
  const int scel = ((lane & 7) ^ (lane >> 3)) << 3;

  // persistent staging pointers: advance +64 elems per staged K-tile
  const bf16* pA[2][2];
  const bf16* pB[2][2];
  #pragma unroll
  for (int h = 0; h < 2; ++h)
    #pragma unroll
    for (int j = 0; j < 2; ++j) {
      pA[h][j] = A  + (size_t)(tileM + h * 128 + srow_lo + j * 64) * K + scel;
      pB[h][j] = Bt + (size_t)(tileN + h * 128 + srow_lo + j * 64) * K + scel;
    }
  const int ldsW = wid * 1024;   // wave's slot within a half-tile

  // stage one half-tile (2 loads) of A at parity par
  auto stA = [&](int par, int h) {
    #pragma unroll
    for (int j = 0; j < 2; ++j) {
      __builtin_amdgcn_global_load_lds(
          (const __attribute__((address_space(1))) void*)pA[h][j],
          (__attribute__((address_space(3))) void*)(lds + par * 32768 + h * 16384 + j * 8192 + ldsW),
          16, 0, 0);
      pA[h][j] += 64;
    }
  };
  auto stB = [&](int par, int h) {
    #pragma unroll
    for (int j = 0; j < 2; ++j) {
      __builtin_amdgcn_global_load_lds(
          (const __attribute__((address_space(1))) void*)pB[h][j],
          (__attribute__((address_space(3))) void*)(lds + 65536 + par * 32768 + h * 16384 + j * 8192 + ldsW),
          16, 0, 0);
      pB[h][j] += 64;
    }
  };

  const int lane15 = lane & 15;
  const int kswz0 = ((lane >> 4) * 16) ^ ((lane & 7) << 4);
  const int aBase = (wm * 128 + lane15) * 128;
  const int bBase = (wn * 64 + lane15) * 128;

  f32x4 acc[8][4] = {};

  // prologue: B(0), A(0), B(1) staged; wait oldest 8 (B0+A0), keep B1 in flight
  stB(0, 0); stB(0, 1); stA(0, 0); stA(0, 1);
  if (NT > 1) { stB(1, 0); stB(1, 1); }
  asm volatile("s_waitcnt vmcnt(4)" : : : "memory");
  __builtin_amdgcn_s_barrier();
  __builtin_amdgcn_sched_barrier(0);

  for (int t = 0; t < NT; ++t) {
    const char* Ab = lds + ((t & 1) << 15);
    const char* Bb = lds + 65536 + ((t & 1) << 15);
    const int parA = (t + 1) & 1;   // parity for A(t+1)
    const int parB = t & 1;         // parity for B(t+2)
    const bool doA = (t + 1 < NT), doB = (t + 2 < NT);
    bf16x8 bfr[4][2];
    #pragma unroll
    for (int q = 0; q < 4; ++q) {
      if (q == 0) {
        #pragma unroll
        for (int n = 0; n < 4; ++n) {
          bfr[n][0] = *(const bf16x8*)(Bb + bBase + n * 2048 + kswz0);
          bfr[n][1] = *(const bf16x8*)(Bb + bBase + n * 2048 + (kswz0 ^ 64));
        }
      }
      bf16x8 am[2][2];
      #pragma unroll
      for (int mm = 0; mm < 2; ++mm) {
        am[mm][0] = *(const bf16x8*)(Ab + aBase + q * 4096 + mm * 2048 + kswz0);
        am[mm][1] = *(const bf16x8*)(Ab + aBase + q * 4096 + mm * 2048 + (kswz0 ^ 64));
      }
      __builtin_amdgcn_sched_barrier(0);
      if (q == 0 && doA) stA(parA, 0);
      if (q == 1) { if (doA) stA(parA, 1); if (doB) stB(parB, 0); }
      if (q == 2 && doB) stB(parB, 1);
      __builtin_amdgcn_sched_barrier(0);
      __builtin_amdgcn_s_barrier();
      __builtin_amdgcn_sched_barrier(0);
      __builtin_amdgcn_s_setprio(1);
      #pragma unroll
      for (int kk = 0; kk < 2; ++kk)
        #pragma unroll
        for (int n = 0; n < 4; ++n) {
          acc[2*q+0][n] = __builtin_amdgcn_mfma_f32_16x16x32_bf16(am[0][kk], bfr[n][kk], acc[2*q+0][n], 0, 0, 0);
          acc[2*q+1][n] = __builtin_amdgcn_mfma_f32_16x16x32_bf16(am[1][kk], bfr[n][kk], acc[2*q+1][n], 0, 0, 0);
        }
      __builtin_amdgcn_s_setprio(0);
      __builtin_amdgcn_sched_barrier(0);
      if (q == 3 && t + 1 < NT) {
        if (t + 2 < NT) asm volatile("s_waitcnt vmcnt(4)" : : : "memory");
        else            asm volatile("s_waitcnt vmcnt(0)" : : : "memory");
      }
      __builtin_amdgcn_s_barrier();
      __builtin_amdgcn_sched_barrier(0);
    }
  }

  const int erow0 = tileM + wm * 128 + (lane >> 4) * 4;
  const int ecol0 = tileN + wn * 64 + lane15;
  #pragma unroll
  for (int m = 0; m < 8; ++m) {
    #pragma unroll
    for (int n = 0; n < 4; ++n) {
      #pragma unroll
      for (int r = 0; r < 4; ++r) {
        const int grow = erow0 + m * 16 + r;
        const int gcol = ecol0 + n * 16;
        const size_t idx = (size_t)grow * N + gcol;
        const float val = acc[m][n][r];
        if constexpr (EPI == 0) {
          outB[idx] = __float2bfloat16(val);
        } else if constexpr (EPI == 1) {
          float tt = fmaxf(val, 0.f);
          outB[idx] = __float2bfloat16(tt * tt);
        } else if constexpr (EPI == 2) {
          outF[idx] = addP[idx] + val;
        } else if constexpr (EPI == 3) {
          outB[idx] = __float2bfloat16(1.f / (1.f + __expf(-val)));
        } else {
          outF[idx] = addP[idx] + __bfloat162float(sigP[idx]) * val;
        }
      }
    }
  }
}

// ---------------- launch ----------------
extern "C" void kernel_launch(void* const* d_in, const int* in_sizes, int n_in,
                              void* d_out, int out_size, void* d_ws, size_t ws_size,
                              hipStream_t stream) {
  const float* x    = (const float*)d_in[0];
  const float* ln1w = (const float*)d_in[1];
  const float* ln1b = (const float*)d_in[2];
  const float* ln2w = (const float*)d_in[3];
  const float* ln2b = (const float*)d_in[4];
  const float* tmk  = (const float*)d_in[5];
  const float* tmv  = (const float*)d_in[6];
  const float* tmr  = (const float*)d_in[7];
  const float* td   = (const float*)d_in[8];
  const float* tf   = (const float*)d_in[9];
  const float* Wk   = (const float*)d_in[10];
  const float* Wv   = (const float*)d_in[11];
  const float* Wr   = (const float*)d_in[12];
  const float* Wo   = (const float*)d_in[13];
  const float* cmk  = (const float*)d_in[14];
  const float* cmr  = (const float*)d_in[15];
  const float* Wck  = (const float*)d_in[16];
  const float* Wcv  = (const float*)d_in[17];
  const float* Wcr  = (const float*)d_in[18];
  float* out = (float*)d_out;

  char* ws = (char*)d_ws;
  const size_t MB = 1ull << 20;
  bf16* R0 = (bf16*)(ws + 0 * MB);
  bf16* R1 = (bf16*)(ws + 32 * MB);
  bf16* R2 = (bf16*)(ws + 64 * MB);
  bf16* R3 = (bf16*)(ws + 96 * MB);
  bf16* R4 = (bf16*)(ws + 128 * MB);

  int S = (ws_size >= 256 * MB) ? 1 : (ws_size >= 192 * MB ? 2 : 4);
  const int FS = F_ / S;

  bf16* xk = R1, *xv = R2, *xr = R3;
  bf16* k_ = R4, *v_ = R1, *r_ = R2, *rwkv = R3;
  bf16* xk2 = R1, *xr2 = R2, *sig = R3, *kf = R4;

  // WKV chunk-state arrays live in R0 (dead during wkv; Wo cvt comes after)
  float* sA = (float*)R0;
  float* sB = sA + (size_t)B_ * NCH * D_;
  float* sP = sB + (size_t)B_ * NCH * D_;

  const int gN2k = (BT_ / 256) * (D_ / 256);   // 256 blocks

  // --- TimeMix ---
  mix1f_kernel<<<BT_, 256, 0, stream>>>(x, ln1w, ln1b, tmk, tmv, tmr, xk, xv, xr);
  cvt_kernel<<<1024, 256, 0, stream>>>(Wk, R0, D_ * C_ / 4);
  gemm256<0><<<gN2k, 512, 0, stream>>>(xk, R0, D_, C_, nullptr, k_, nullptr, nullptr);
  cvt_kernel<<<1024, 256, 0, stream>>>(Wv, R0, D_ * C_ / 4);
  gemm256<0><<<gN2k, 512, 0, stream>>>(xv, R0, D_, C_, nullptr, v_, nullptr, nullptr);
  cvt_kernel<<<1024, 256, 0, stream>>>(Wr, R0, D_ * C_ / 4);
  gemm256<0><<<gN2k, 512, 0, stream>>>(xr, R0, D_, C_, nullptr, r_, nullptr, nullptr);
  wkv_pass1<<<B_ * NCH * D_ / 256, 256, 0, stream>>>(k_, v_, td, sA, sB, sP);
  wkv_pass2<<<B_ * D_ / 256, 256, 0, stream>>>(td, sA, sB, sP);
  wkv_pass3<<<B_ * NCH * D_ / 256, 256, 0, stream>>>(k_, v_, r_, td, tf, sA, sB, sP, rwkv);
  cvt_kernel<<<1024, 256, 0, stream>>>(Wo, R0, C_ * D_ / 4);
  gemm256<2><<<gN2k, 512, 0, stream>>>(rwkv, R0, C_, D_, out, nullptr, x, nullptr);

  // --- ChannelMix ---
  mix2f_kernel<<<BT_, 256, 0, stream>>>(out, ln2w, ln2b, cmk, cmr, xk2, xr2);
  cvt_kernel<<<1024, 256, 0, stream>>>(Wcr, R0, C_ * C_ / 4);
  gemm256<3><<<gN2k, 512, 0, stream>>>(xr2, R0, C_, C_, nullptr, sig, nullptr, nullptr);
  for (int h = 0; h < S; ++h) {
    cvt_kernel<<<1024, 256, 0, stream>>>(Wck + (size_t)h * FS * C_, R0, FS * C_ / 4);
    gemm256<1><<<(BT_/256) * (FS/256), 512, 0, stream>>>(xk2, R0, FS, C_, nullptr, kf, nullptr, nullptr);
    packcvt_kernel<<<1024, 256, 0, stream>>>(Wcv, R0, C_, FS, F_, h * FS);
    gemm256<4><<<gN2k, 512, 0, stream>>>(kf, R0, C_, FS, out, nullptr, out, sig);
  }
}